// Round 2
// baseline (695.183 us; speedup 1.0000x reference)
//
#include <hip/hip_runtime.h>

// Problem constants (from reference)
#define NTOKENS    8192
#define TOPK       2
#define HIDDEN     4096
#define NUM_GROUPS 2
#define M_FULL     (NTOKENS * TOPK)   // 16384
#define H4         (HIDDEN / 4)       // 1024 float4 per row
#define TPB        256
#define NBLOCKS    2048               // 8 blocks/CU, grid-stride over 4 tokens each
#define CHUNK      (H4 / TPB)         // 4 chunks of 4 KB (256 thr x 16 B)

// Native clang vector type: required for __builtin_nontemporal_*
typedef float f32x4 __attribute__((ext_vector_type(4)));

// out[t,h] = sum_{g,k} buf[g, idx[t,k], h]
//
// Structure: persistent 2048-block grid; each block handles tokens
// t, t+2048, t+4096, t+6144 with the NEXT token's indices prefetched
// before the current token's body.
//
// Key change vs the 691 us baseline: the 4 gather streams are
// phase-rotated by one 4 KB chunk each (acc[] register accumulation
// keeps indexing static), so the five 16 KB-aligned streams of a block
// no longer march in lockstep through identical low-14-bit addresses.
__global__ __launch_bounds__(TPB) void topk_gather_rs_kernel(
    const f32x4* __restrict__ buf,    // (NUM_GROUPS, M_FULL, H4) as f32x4
    const int*   __restrict__ idx,    // (NTOKENS, TOPK)
    f32x4*       __restrict__ out)    // (NTOKENS, H4)
{
    const int tid = threadIdx.x;
    const size_t g1off = (size_t)M_FULL * H4;   // group-1 base offset in f32x4 units

    int t = blockIdx.x;
    // idx index is block-uniform -> compiler scalarizes to s_load
    int r0 = idx[t * TOPK + 0];
    int r1 = idx[t * TOPK + 1];

    while (t < NTOKENS) {
        // ---- prefetch next token's indices (hide idx->gather dependency) ----
        const int nt = t + NBLOCKS;
        int nr0 = 0, nr1 = 0;
        if (nt < NTOKENS) {
            nr0 = idx[nt * TOPK + 0];
            nr1 = idx[nt * TOPK + 1];
        }

        const f32x4* __restrict__ p00 = buf + (size_t)r0 * H4;          // g0, k0
        const f32x4* __restrict__ p01 = buf + (size_t)r1 * H4;          // g0, k1
        const f32x4* __restrict__ p10 = buf + g1off + (size_t)r0 * H4;  // g1, k0
        const f32x4* __restrict__ p11 = buf + g1off + (size_t)r1 * H4;  // g1, k1
        f32x4* __restrict__ o = out + (size_t)t * H4;

        f32x4 acc[CHUNK];
#pragma unroll
        for (int j = 0; j < CHUNK; ++j) {
            acc[j] = (f32x4)(0.f);
        }

        // Phase-rotated gather: stream s starts at chunk (j+s)&3.
        // All acc[] indices are compile-time constants after unrolling.
#pragma unroll
        for (int j = 0; j < CHUNK; ++j) {
            const int k0 = (j + 0) & (CHUNK - 1);
            const int k1 = (j + 1) & (CHUNK - 1);
            const int k2 = (j + 2) & (CHUNK - 1);
            const int k3 = (j + 3) & (CHUNK - 1);

            const f32x4 a = p00[k0 * TPB + tid];
            const f32x4 b = p01[k1 * TPB + tid];
            const f32x4 c = p10[k2 * TPB + tid];
            const f32x4 d = p11[k3 * TPB + tid];

            acc[k0] += a;
            acc[k1] += b;
            acc[k2] += c;
            acc[k3] += d;
        }

        // Nontemporal stores: out is never re-read; keep L2/LLC for the
        // ~37% duplicated gather rows.
#pragma unroll
        for (int j = 0; j < CHUNK; ++j) {
            __builtin_nontemporal_store(acc[j], &o[j * TPB + tid]);
        }

        t  = nt;
        r0 = nr0;
        r1 = nr1;
    }
}

extern "C" void kernel_launch(void* const* d_in, const int* in_sizes, int n_in,
                              void* d_out, int out_size, void* d_ws, size_t ws_size,
                              hipStream_t stream) {
    const f32x4* buf = (const f32x4*)d_in[0];
    const int*   idx = (const int*)d_in[1];
    f32x4*       out = (f32x4*)d_out;

    topk_gather_rs_kernel<<<NBLOCKS, TPB, 0, stream>>>(buf, idx, out);
}

// Round 3
// 694.295 us; speedup vs baseline: 1.0013x; 1.0013x over previous
//
#include <hip/hip_runtime.h>

// Problem constants (from reference)
#define NTOKENS    8192
#define TOPK       2
#define HIDDEN     4096
#define NUM_GROUPS 2
#define M_FULL     (NTOKENS * TOPK)   // 16384
#define H4         (HIDDEN / 4)       // 1024 float4 per row
#define TPB        256                // 4 waves
#define NBLOCKS    512                // 2 blocks/CU -> 2560 concurrent streams (was 10240)

typedef float f32x4 __attribute__((ext_vector_type(4)));

// out[t,h] = sum_{g,k} buf[g, idx[t,k], h]
//
// Theory: the gather is DRAM-row-thrash limited (~2 TB/s effective) due to
// thousands of interleaved 16 KB random streams. This version:
//  - 512 persistent blocks (16 tokens each), not 2048/8192: 4x fewer
//    concurrent streams at the memory controllers.
//  - wave-contiguous mapping: each wave owns a contiguous 4 KB quarter-row
//    and issues its 4x1KB loads per stream back-to-back (stream-major),
//    giving 4x longer sequential runs per DRAM bank than the strided map.
//  - plain stores (NT stores reverted: no gain, absmax regression).
//  - baseline summation order (a+b)+(c+d) restored -> expect absmax 0.0.
__global__ __launch_bounds__(TPB) void topk_gather_rs_kernel(
    const f32x4* __restrict__ buf,    // (NUM_GROUPS, M_FULL, H4) as f32x4
    const int*   __restrict__ idx,    // (NTOKENS, TOPK)
    f32x4*       __restrict__ out)    // (NTOKENS, H4)
{
    const int tid  = threadIdx.x;
    const int lane = tid & 63;
    const int wave = tid >> 6;
    // Wave w owns f32x4 columns [w*256, w*256+256) = one contiguous 4 KB quarter.
    const int base = wave * 256 + lane;
    const size_t g1off = (size_t)M_FULL * H4;

    int t = blockIdx.x;
    int r0 = idx[t * TOPK + 0];
    int r1 = idx[t * TOPK + 1];

    while (t < NTOKENS) {
        // prefetch next token's indices (hide idx->gather dependency)
        const int nt = t + NBLOCKS;
        int nr0 = 0, nr1 = 0;
        if (nt < NTOKENS) {
            nr0 = idx[nt * TOPK + 0];
            nr1 = idx[nt * TOPK + 1];
        }

        const f32x4* __restrict__ p00 = buf + (size_t)r0 * H4 + base;          // g0,k0
        const f32x4* __restrict__ p01 = buf + (size_t)r1 * H4 + base;          // g0,k1
        const f32x4* __restrict__ p10 = p00 + g1off;                           // g1,k0
        const f32x4* __restrict__ p11 = p01 + g1off;                           // g1,k1
        f32x4* __restrict__ o = out + (size_t)t * H4 + base;

        f32x4 a[4], b[4], c[4], d[4];
        // Stream-major issue: 4 back-to-back 1 KB wave-loads per stream,
        // covering the wave's contiguous 4 KB quarter of each row.
#pragma unroll
        for (int i = 0; i < 4; ++i) a[i] = p00[i * 64];
#pragma unroll
        for (int i = 0; i < 4; ++i) b[i] = p01[i * 64];
#pragma unroll
        for (int i = 0; i < 4; ++i) c[i] = p10[i * 64];
#pragma unroll
        for (int i = 0; i < 4; ++i) d[i] = p11[i * 64];

#pragma unroll
        for (int i = 0; i < 4; ++i) {
            o[i * 64] = (a[i] + b[i]) + (c[i] + d[i]);
        }

        t  = nt;
        r0 = nr0;
        r1 = nr1;
    }
}

extern "C" void kernel_launch(void* const* d_in, const int* in_sizes, int n_in,
                              void* d_out, int out_size, void* d_ws, size_t ws_size,
                              hipStream_t stream) {
    const f32x4* buf = (const f32x4*)d_in[0];
    const int*   idx = (const int*)d_in[1];
    f32x4*       out = (f32x4*)d_out;

    topk_gather_rs_kernel<<<NBLOCKS, TPB, 0, stream>>>(buf, idx, out);
}